// Round 7
// baseline (796.937 us; speedup 1.0000x reference)
//
#include <hip/hip_runtime.h>
#include <math.h>

#define NN 20000
#define H 256
#define R 64
#define EE 320000
#define LN_EPS 1e-5f
#define NB 79   // ceil(NN/256)

using short8  = __attribute__((ext_vector_type(8))) short;
using ushort8 = __attribute__((ext_vector_type(8))) unsigned short;
using f32x4   = __attribute__((ext_vector_type(4))) float;
using half8   = __attribute__((ext_vector_type(8))) _Float16;

typedef __attribute__((address_space(3))) unsigned int lds_uint;
typedef const __attribute__((address_space(1))) unsigned int glb_uint;

__device__ __forceinline__ float silu_f(float x) {
    return x * __builtin_amdgcn_rcpf(1.0f + __expf(-x));
}

// round-to-nearest-even fp32 -> bf16 (as ushort)
__device__ __forceinline__ unsigned short f2bf(float f) {
    unsigned u = __float_as_uint(f);
    u += 0x7fff + ((u >> 16) & 1);
    return (unsigned short)(u >> 16);
}
__device__ __forceinline__ float bf2f(unsigned short s) {
    return __uint_as_float(((unsigned)s) << 16);
}
// f32 <-> f16 (RNE) via v_cvt
__device__ __forceinline__ unsigned short f2h(float f) {
    unsigned r;
    asm("v_cvt_f16_f32 %0, %1" : "=v"(r) : "v"(f));
    return (unsigned short)r;
}

// XOR-swizzled LDS index for [row][64] short arrays (bf16 fragments)
__device__ __forceinline__ int sw_idx(int row, int col) {
    return row * 64 + ((((col >> 3) ^ (row & 7)) << 3) | (col & 7));
}
// dks f16 [64][256]: xor col bits[5:4] by row bits[3:2]. XOR touches only
// bits >=4, so any 8-element run at col%8==0 stays contiguous/16B-aligned.
__device__ __forceinline__ int dh_idx(int row, int col) {
    return row * 256 + (col ^ (((row >> 2) & 3) << 4));
}

// ---------------------------------------------------------------------------
// Combined prep (one launch, 242 blocks)
// ---------------------------------------------------------------------------
__global__ __launch_bounds__(256) void k_prep(
    const float* __restrict__ Wq, const float* __restrict__ Wk,
    const float* __restrict__ Wv, const float* __restrict__ Wo,
    const float* __restrict__ g,  const float* __restrict__ b,
    const float* __restrict__ bq, const float* __restrict__ bk, const float* __restrict__ bv,
    const float* __restrict__ Wdk, const float* __restrict__ Wdv,
    unsigned short* __restrict__ wqkv_p, unsigned short* __restrict__ wo_p,
    unsigned short* __restrict__ wdk_p,  unsigned short* __restrict__ wdv_p,
    float* __restrict__ bias3, int* __restrict__ hist)
{
    const int bid = blockIdx.x, t = threadIdx.x;
    if (bid < 128) {
        const int mat = bid >> 5;
        const float* W = mat == 0 ? Wq : (mat == 1 ? Wk : (mat == 2 ? Wv : Wo));
        unsigned short* out = (mat < 3) ? wqkv_p + (size_t)mat * 131072 : wo_p;
        const int fold = mat < 3;
        const int flat = (bid & 31) * 256 + t;           // [0, 8192)
        const int tile = flat >> 9;
        const int rem  = flat & 511;
        const int ks   = rem >> 6;
        const int lane = rem & 63;
        const int nl = lane & 15, quad = lane >> 4;
        const int h  = tile * 16 + nl;
        const int c0 = ks * 32 + quad * 8;
        short8 hi8, lo8;
        #pragma unroll
        for (int j = 0; j < 8; ++j) {
            float wv = W[(size_t)h * 256 + c0 + j];
            if (fold) wv *= g[c0 + j];
            const unsigned short hh = f2bf(wv);
            hi8[j] = (short)hh;
            lo8[j] = (short)f2bf(wv - bf2f(hh));
        }
        unsigned short* ob = out + ((size_t)(tile * 8 + ks)) * 1024;
        *(short8*)&ob[lane * 8] = hi8;
        *(short8*)&ob[512 + lane * 8] = lo8;
    } else if (bid < 160) {
        const int flat = (bid - 128) * 256 + t;          // [0, 8192)
        const int mat  = flat >> 12;
        const int rem  = flat & 4095;
        const int hh   = rem >> 11;
        const int r2   = rem & 2047;
        const int row  = r2 >> 4;
        const int col4 = (r2 & 15) * 4;
        const float* W = mat == 0 ? Wdk : Wdv;
        unsigned short* out = (mat == 0 ? wdk_p : wdv_p) + hh * 16384;
        const float4 w4 = *(const float4*)(W + (size_t)(hh * 128 + row) * 64 + col4);
        const unsigned short h0 = f2bf(w4.x), h1 = f2bf(w4.y), h2 = f2bf(w4.z), h3 = f2bf(w4.w);
        ushort4 hi4 = {h0, h1, h2, h3};
        ushort4 lo4 = {f2bf(w4.x - bf2f(h0)), f2bf(w4.y - bf2f(h1)),
                       f2bf(w4.z - bf2f(h2)), f2bf(w4.w - bf2f(h3))};
        const int di = sw_idx(row, col4);
        *(ushort4*)&out[di] = hi4;
        *(ushort4*)&out[8192 + di] = lo4;
    } else if (bid < 163) {
        const int mat = bid - 160, h = t;
        const float* W  = mat == 0 ? Wq : (mat == 1 ? Wk : Wv);
        const float* bb = mat == 0 ? bq : (mat == 1 ? bk : bv);
        float s = 0.f;
        const float* wr = W + (size_t)h * 256;
        for (int c = 0; c < 256; c += 4) {
            const float4 w4 = *(const float4*)(wr + c);
            const float4 b4 = *(const float4*)(b + c);
            s += w4.x * b4.x + w4.y * b4.y + w4.z * b4.z + w4.w * b4.w;
        }
        bias3[mat * 256 + h] = bb[h] + s;
    } else {
        const int i = (bid - 163) * 256 + t;
        if (i < NN) hist[i] = 0;
    }
}

// ---------------------------------------------------------------------------
// K1: LayerNorm + QKV via split-bf16 MFMA. 16 nodes per 64-thread block.
// Round-13: q/k/v stored as f16 (halves k_edge gather bytes + own stores).
// ---------------------------------------------------------------------------
__global__ __launch_bounds__(64, 2) void k_ln_qkv(
    const float* __restrict__ x,
    const unsigned short* __restrict__ wqkv_p, const float* __restrict__ bias3,
    unsigned short* __restrict__ q, unsigned short* __restrict__ k,
    unsigned short* __restrict__ v)
{
    const int t = threadIdx.x;
    const int lane = t & 63;
    const int nl = lane & 15, quad = lane >> 4;
    const int nbase = blockIdx.x * 16;
    const int node = nbase + nl;
    const bool nv = node < NN;

    float xv[64];
    float sum = 0.f, sq = 0.f;
    {
        const float* xp = x + (size_t)node * H + quad * 8;
        #pragma unroll
        for (int ks = 0; ks < 8; ++ks) {
            float4 x0 = {0.f,0.f,0.f,0.f}, x1 = {0.f,0.f,0.f,0.f};
            if (nv) {
                x0 = *(const float4*)(xp + ks * 32);
                x1 = *(const float4*)(xp + ks * 32 + 4);
            }
            xv[ks*8+0]=x0.x; xv[ks*8+1]=x0.y; xv[ks*8+2]=x0.z; xv[ks*8+3]=x0.w;
            xv[ks*8+4]=x1.x; xv[ks*8+5]=x1.y; xv[ks*8+6]=x1.z; xv[ks*8+7]=x1.w;
            sum += x0.x+x0.y+x0.z+x0.w + x1.x+x1.y+x1.z+x1.w;
            sq  += x0.x*x0.x+x0.y*x0.y+x0.z*x0.z+x0.w*x0.w
                 + x1.x*x1.x+x1.y*x1.y+x1.z*x1.z+x1.w*x1.w;
        }
    }
    sum += __shfl_xor(sum, 16); sum += __shfl_xor(sum, 32);
    sq  += __shfl_xor(sq, 16);  sq  += __shfl_xor(sq, 32);
    const float mu  = sum * (1.0f / H);
    const float var = sq * (1.0f / H) - mu * mu;
    const float rs  = rsqrtf(var + LN_EPS);

    short8 a_hi[8], a_lo[8];
    #pragma unroll
    for (int ks = 0; ks < 8; ++ks) {
        #pragma unroll
        for (int j = 0; j < 8; ++j) {
            const float z = (xv[ks*8+j] - mu) * rs;
            const unsigned short hh = f2bf(z);
            a_hi[ks][j] = (short)hh;
            a_lo[ks][j] = (short)f2bf(z - bf2f(hh));
        }
    }

    for (int mat = 0; mat < 3; ++mat) {
        unsigned short* outp = mat == 0 ? q : (mat == 1 ? k : v);
        const float* bp = bias3 + mat * 256;
        const unsigned short* wb = wqkv_p + (size_t)mat * 131072 + lane * 8;
        for (int tile = 0; tile < 16; ++tile) {
            const unsigned short* gb = wb + (size_t)tile * 8192;
            const float bbv = bp[tile * 16 + nl];
            f32x4 acc = {bbv, bbv, bbv, bbv};
            #pragma unroll
            for (int ks = 0; ks < 8; ++ks) {
                const short8 b_hi = *(const short8*)(gb + ks * 1024);
                const short8 b_lo = *(const short8*)(gb + ks * 1024 + 512);
                acc = __builtin_amdgcn_mfma_f32_16x16x32_bf16(a_hi[ks], b_hi, acc, 0, 0, 0);
                acc = __builtin_amdgcn_mfma_f32_16x16x32_bf16(a_lo[ks], b_hi, acc, 0, 0, 0);
                acc = __builtin_amdgcn_mfma_f32_16x16x32_bf16(a_hi[ks], b_lo, acc, 0, 0, 0);
            }
            #pragma unroll
            for (int r = 0; r < 4; ++r) {
                const int onode = nbase + quad * 4 + r;
                if (onode < NN)
                    outp[(size_t)onode * H + tile * 16 + nl] = f2h(acc[r]);
            }
        }
    }
}

// ---------------------------------------------------------------------------
// Counting sort of edges by dst: hist -> scan -> scatter(perm)
// ---------------------------------------------------------------------------
__global__ __launch_bounds__(256) void k_hist(const int* __restrict__ ei, int* __restrict__ hist) {
    int e = blockIdx.x * 256 + threadIdx.x;
    if (e < EE) atomicAdd(&hist[ei[EE + e]], 1);
}

__global__ __launch_bounds__(256) void k_scan1(const int* __restrict__ hist,
                                               int* __restrict__ cursor, int* __restrict__ bsum) {
    const int t = threadIdx.x, i = blockIdx.x * 256 + t;
    const int lane = t & 63, w = t >> 6;
    const int v = (i < NN) ? hist[i] : 0;
    int incl = v;
    #pragma unroll
    for (int off = 1; off < 64; off <<= 1) {
        int u = __shfl_up(incl, off);
        if (lane >= off) incl += u;
    }
    __shared__ int ws[4];
    if (lane == 63) ws[w] = incl;
    __syncthreads();
    int base = 0;
    #pragma unroll
    for (int j = 0; j < 4; ++j) if (j < w) base += ws[j];
    if (i < NN) cursor[i] = base + incl - v;
    if (t == 255) bsum[blockIdx.x] = base + incl;
}

__global__ __launch_bounds__(128) void k_scan2(int* __restrict__ bsum) {
    __shared__ int buf[128];
    const int t = threadIdx.x;
    const int v = (t < NB) ? bsum[t] : 0;
    buf[t] = v;
    __syncthreads();
    #pragma unroll
    for (int off = 1; off < 128; off <<= 1) {
        int add = (t >= off) ? buf[t - off] : 0;
        __syncthreads();
        buf[t] += add;
        __syncthreads();
    }
    if (t < NB) bsum[t] = buf[t] - v;
}

// scan3 folded in: final position = local prefix (cursor) + block base (bsum)
__global__ __launch_bounds__(256) void k_scatter(const int* __restrict__ ei,
                                                 int* __restrict__ cursor,
                                                 const int* __restrict__ bsum,
                                                 int* __restrict__ perm) {
    int e = blockIdx.x * 256 + threadIdx.x;
    if (e < EE) {
        int d = ei[EE + e];
        int pos = atomicAdd(&cursor[d], 1) + bsum[d >> 8];
        perm[pos] = e;
    }
}

// ---------------------------------------------------------------------------
// K2: round-13 -- register PREFETCH of all gathers + f16 q/k/v.
// Gather addresses are known at block start; issue k/q row loads right after
// the first barrier so they land under the two dk MFMA/staging phases; issue
// v row loads after pass A so they land under the two dv phases. Pass A/B
// become pure register+LDS compute -- no exposed gather latency.
// Thread owns 8 contiguous cols (c8=tx*8): one ushort8/row (16B) load.
// ---------------------------------------------------------------------------
__global__ __launch_bounds__(256, 2) void k_edge(
    const unsigned short* __restrict__ q16, const unsigned short* __restrict__ k16,
    const unsigned short* __restrict__ v16,
    const int* __restrict__ ei, const float* __restrict__ ew, const float* __restrict__ ea,
    const unsigned short* __restrict__ wdk_p, const float* __restrict__ bdk,
    const unsigned short* __restrict__ wdv_p, const float* __restrict__ bdv,
    const int* __restrict__ perm,
    float* __restrict__ agg)
{
    __shared__ __align__(16) unsigned short w_region[2 * 128 * 64];  // 32 KB hi|lo
    __shared__ __align__(16) unsigned short dks_h[64 * 256];         // 32 KB f16, both halves
    __shared__ float attn_s[64];
    __shared__ int src_s[64], dst_s[64];

    const unsigned short* w_hi_s = w_region;
    const unsigned short* w_lo_s = w_region + 128 * 64;

    const int t    = threadIdx.x;
    const int bi   = blockIdx.x;
    const int eb   = ((bi & 7) * 625 + (bi >> 3)) * 64;   // XCD-contiguous chunks
    const int lane = t & 63, wave = t >> 6;
    const int nl   = lane & 15, quad = lane >> 4;
    const int estrip = wave * 16;
    const int tx = t & 31, ty = t >> 5;
    const int c8 = tx * 8, e0 = ty * 8;

    #define STAGE(PTR)                                                                \
    {                                                                                 \
        const ushort8* sp = (const ushort8*)(PTR) + t;                                \
        ushort8* dpw = (ushort8*)w_region + (t & 192);                                \
        _Pragma("unroll")                                                             \
        for (int c = 0; c < 8; ++c)                                                   \
            __builtin_amdgcn_global_load_lds((glb_uint*)(sp + c * 256),               \
                                             (lds_uint*)(dpw + c * 256), 16, 0, 0);   \
    }

    #define MFMA_TO_DKS(BIAS, HALF)                                                   \
    {                                                                                 \
        f32x4 accA[8];                                                                \
        _Pragma("unroll")                                                             \
        for (int tt = 0; tt < 8; ++tt) {                                              \
            const int wrow = tt * 16 + nl;                                            \
            short8 b_hi[2], b_lo[2];                                                  \
            _Pragma("unroll")                                                         \
            for (int ks = 0; ks < 2; ++ks) {                                          \
                const int idx = wrow * 64 + ((((ks * 4 + quad) ^ (nl & 7)) << 3));    \
                b_hi[ks] = *(const short8*)&w_hi_s[idx];                              \
                b_lo[ks] = *(const short8*)&w_lo_s[idx];                              \
            }                                                                         \
            const float bb = (BIAS)[(HALF) * 128 + tt * 16 + nl];                     \
            f32x4 acc = {bb, bb, bb, bb};                                             \
            _Pragma("unroll")                                                         \
            for (int ks = 0; ks < 2; ++ks) {                                          \
                acc = __builtin_amdgcn_mfma_f32_16x16x32_bf16(a_hi[ks], b_hi[ks], acc, 0, 0, 0); \
                acc = __builtin_amdgcn_mfma_f32_16x16x32_bf16(a_lo[ks], b_hi[ks], acc, 0, 0, 0); \
                acc = __builtin_amdgcn_mfma_f32_16x16x32_bf16(a_hi[ks], b_lo[ks], acc, 0, 0, 0); \
            }                                                                         \
            accA[tt] = acc;                                                           \
        }                                                                             \
        __syncthreads();  /* all waves done reading w_region */                       \
        _Pragma("unroll")                                                             \
        for (int tt = 0; tt < 8; ++tt)                                                \
            _Pragma("unroll")                                                         \
            for (int r = 0; r < 4; ++r)                                               \
                dks_h[dh_idx(estrip + quad * 4 + r, (HALF) * 128 + tt * 16 + nl)] =   \
                    f2h(silu_f(accA[tt][r]));                                         \
    }

    // stage image 0 (wdk half 0)
    STAGE(wdk_p);

    if (t < 64) {
        const int e = perm[eb + t];
        src_s[t] = ei[e];
        dst_s[t] = ei[EE + e];
    }

    // ea A-fragments straight from global, in-register hi/lo split
    short8 a_hi[2], a_lo[2];
    {
        const int e = perm[eb + estrip + nl];
        const float* ap = ea + (size_t)e * R + quad * 8;
        #pragma unroll
        for (int ks = 0; ks < 2; ++ks) {
            const f32x4 x0 = *(const f32x4*)(ap + ks * 32);
            const f32x4 x1 = *(const f32x4*)(ap + ks * 32 + 4);
            const float zz[8] = {x0[0], x0[1], x0[2], x0[3], x1[0], x1[1], x1[2], x1[3]};
            #pragma unroll
            for (int j = 0; j < 8; ++j) {
                const unsigned short hv = f2bf(zz[j]);
                a_hi[ks][j] = (short)hv;
                a_lo[ks][j] = (short)f2bf(zz[j] - bf2f(hv));
            }
        }
    }
    __syncthreads();   // image dk.h0 landed; src/dst visible

    // PREFETCH: k and q rows for my 8 edges -- land under the dk phases
    half8 kj8[8], qi8[8];
    #pragma unroll
    for (int i = 0; i < 8; ++i) {
        const int s = src_s[e0 + i], d = dst_s[e0 + i];
        kj8[i] = *(const half8*)(k16 + (size_t)s * H + c8);
        qi8[i] = *(const half8*)(q16 + (size_t)d * H + c8);
    }

    // ---- dk half 0 ---- (manual: STAGE must sit between barrier and dks write)
    {
        f32x4 accA[8];
        #pragma unroll
        for (int tt = 0; tt < 8; ++tt) {
            const int wrow = tt * 16 + nl;
            short8 b_hi[2], b_lo[2];
            #pragma unroll
            for (int ks = 0; ks < 2; ++ks) {
                const int idx = wrow * 64 + ((((ks * 4 + quad) ^ (nl & 7)) << 3));
                b_hi[ks] = *(const short8*)&w_hi_s[idx];
                b_lo[ks] = *(const short8*)&w_lo_s[idx];
            }
            const float bb = bdk[tt * 16 + nl];
            f32x4 acc = {bb, bb, bb, bb};
            #pragma unroll
            for (int ks = 0; ks < 2; ++ks) {
                acc = __builtin_amdgcn_mfma_f32_16x16x32_bf16(a_hi[ks], b_hi[ks], acc, 0, 0, 0);
                acc = __builtin_amdgcn_mfma_f32_16x16x32_bf16(a_lo[ks], b_hi[ks], acc, 0, 0, 0);
                acc = __builtin_amdgcn_mfma_f32_16x16x32_bf16(a_hi[ks], b_lo[ks], acc, 0, 0, 0);
            }
            accA[tt] = acc;
        }
        __syncthreads();           // w_region free
        STAGE(wdk_p + 16384);      // dk half 1
        #pragma unroll
        for (int tt = 0; tt < 8; ++tt)
            #pragma unroll
            for (int r = 0; r < 4; ++r)
                dks_h[dh_idx(estrip + quad * 4 + r, tt * 16 + nl)] =
                    f2h(silu_f(accA[tt][r]));
    }
    __syncthreads();               // dk.h1 landed
    MFMA_TO_DKS(bdk, 1);
    STAGE(wdv_p);                  // dv half 0 -- lands during pass A

    // ---- pass A: pure register+LDS compute (own wave's dks rows) ----
    #pragma unroll
    for (int i = 0; i < 8; ++i) {
        const half8 qk = qi8[i] * kj8[i];                // v_pk_mul_f16
        const half8 dd = *(const half8*)&dks_h[dh_idx(e0 + i, c8)];
        float part = 0.f;
        #pragma unroll
        for (int j = 0; j < 8; ++j)
            part += (float)qk[j] * (float)dd[j];
        #pragma unroll
        for (int off = 16; off; off >>= 1) part += __shfl_xor(part, off);
        if (tx == 0) attn_s[e0 + i] = part;
    }

    // PREFETCH: v rows -- land under the dv phases
    half8 vj8[8];
    #pragma unroll
    for (int i = 0; i < 8; ++i)
        vj8[i] = *(const half8*)(v16 + (size_t)src_s[e0 + i] * H + c8);

    __syncthreads();               // pass A visible; dv.h0 landed

    // attn finalize (wave 0); published by the next macro's internal barrier
    if (t < 64) {
        const int e = perm[eb + t];
        const float rr = ew[e];
        const float cut = (rr < 5.0f) ? 0.5f * (__cosf(rr * 0.6283185307f) + 1.0f) : 0.0f;
        attn_s[t] = silu_f(attn_s[t]) * cut;
    }

    MFMA_TO_DKS(bdv, 0);
    STAGE(wdv_p + 16384);          // dv half 1
    __syncthreads();               // dv.h1 landed
    MFMA_TO_DKS(bdv, 1);

    // ---- pass B: run-flush from registers (own wave's dks rows; attn
    // published by the dv.h0 macro barrier) ----
    {
        float m[8] = {0.f,0.f,0.f,0.f,0.f,0.f,0.f,0.f};
        int cur_d = -1;
        #pragma unroll
        for (int i = 0; i < 8; ++i) {
            const int d = dst_s[e0 + i];
            const float a = attn_s[e0 + i];
            const half8 vd = vj8[i] * *(const half8*)&dks_h[dh_idx(e0 + i, c8)];
            if (d != cur_d) {
                if (cur_d >= 0) {
                    float* dp = agg + (size_t)cur_d * H + c8;
                    #pragma unroll
                    for (int j = 0; j < 8; ++j) atomicAdd(dp + j, m[j]);
                }
                #pragma unroll
                for (int j = 0; j < 8; ++j) m[j] = (float)vd[j] * a;
                cur_d = d;
            } else {
                #pragma unroll
                for (int j = 0; j < 8; ++j) m[j] += (float)vd[j] * a;
            }
        }
        {
            float* dp = agg + (size_t)cur_d * H + c8;
            #pragma unroll
            for (int j = 0; j < 8; ++j) atomicAdd(dp + j, m[j]);
        }
    }
    #undef MFMA_TO_DKS
    #undef STAGE
}

// ---------------------------------------------------------------------------
// K3: out = x + agg @ Wo'^T + bo via split-bf16 MFMA. 16 nodes / 64-thr block.
// ---------------------------------------------------------------------------
__global__ __launch_bounds__(64, 2) void k_out(
    const float* __restrict__ aggm, const unsigned short* __restrict__ wo_p,
    const float* __restrict__ bo, const float* __restrict__ x, float* __restrict__ out)
{
    const int t = threadIdx.x;
    const int lane = t & 63;
    const int nl = lane & 15, quad = lane >> 4;
    const int nbase = blockIdx.x * 16;
    const int node = nbase + nl;
    const bool nv = node < NN;

    short8 a_hi[8], a_lo[8];
    {
        const float* ap = aggm + (size_t)node * H + quad * 8;
        #pragma unroll
        for (int ks = 0; ks < 8; ++ks) {
            float4 x0 = {0.f,0.f,0.f,0.f}, x1 = {0.f,0.f,0.f,0.f};
            if (nv) { x0 = *(const float4*)(ap + ks * 32); x1 = *(const float4*)(ap + ks * 32 + 4); }
            const float zz[8] = {x0.x,x0.y,x0.z,x0.w,x1.x,x1.y,x1.z,x1.w};
            #pragma unroll
            for (int j = 0; j < 8; ++j) {
                const unsigned short hh = f2bf(zz[j]);
                a_hi[ks][j] = (short)hh;
                a_lo[ks][j] = (short)f2bf(zz[j] - bf2f(hh));
            }
        }
    }
    for (int tile = 0; tile < 16; ++tile) {
        const unsigned short* gb = wo_p + (size_t)tile * 8192 + lane * 8;
        const float bbv = bo[tile * 16 + nl];
        f32x4 acc = {bbv, bbv, bbv, bbv};
        #pragma unroll
        for (int ks = 0; ks < 8; ++ks) {
            const short8 b_hi = *(const short8*)(gb + ks * 1024);
            const short8 b_lo = *(const short8*)(gb + ks * 1024 + 512);
            acc = __builtin_amdgcn_mfma_f32_16x16x32_bf16(a_hi[ks], b_hi, acc, 0, 0, 0);
            acc = __builtin_amdgcn_mfma_f32_16x16x32_bf16(a_lo[ks], b_hi, acc, 0, 0, 0);
            acc = __builtin_amdgcn_mfma_f32_16x16x32_bf16(a_hi[ks], b_lo, acc, 0, 0, 0);
        }
        #pragma unroll
        for (int r = 0; r < 4; ++r) {
            const int onode = nbase + quad * 4 + r;
            if (onode < NN) {
                const size_t oi = (size_t)onode * H + tile * 16 + nl;
                out[oi] = x[oi] + acc[r];
            }
        }
    }
}

extern "C" void kernel_launch(void* const* d_in, const int* in_sizes, int n_in,
                              void* d_out, int out_size, void* d_ws, size_t ws_size,
                              hipStream_t stream) {
    const float* x   = (const float*)d_in[0];
    const int*   ei  = (const int*)d_in[1];
    const float* ew  = (const float*)d_in[2];
    const float* ea  = (const float*)d_in[3];
    const float* g   = (const float*)d_in[4];
    const float* b   = (const float*)d_in[5];
    const float* Wq  = (const float*)d_in[6];  const float* bq  = (const float*)d_in[7];
    const float* Wk  = (const float*)d_in[8];  const float* bk  = (const float*)d_in[9];
    const float* Wv  = (const float*)d_in[10]; const float* bv  = (const float*)d_in[11];
    const float* Wo  = (const float*)d_in[12]; const float* bo  = (const float*)d_in[13];
    const float* Wdk = (const float*)d_in[14]; const float* bdk = (const float*)d_in[15];
    const float* Wdv = (const float*)d_in[16]; const float* bdv = (const float*)d_in[17];

    unsigned short* q16 = (unsigned short*)d_ws;
    unsigned short* k16 = q16 + (size_t)NN * H;
    unsigned short* v16 = k16 + (size_t)NN * H;
    float* agg  = (float*)(v16 + (size_t)NN * H);
    int*   hist = (int*)(agg + (size_t)NN * H);
    int*   cur  = hist + NN;
    int*   bsum = cur + NN;
    int*   perm = bsum + 128;
    unsigned short* wqkv_p = (unsigned short*)(perm + EE);
    unsigned short* wo_p   = wqkv_p + 393216;
    unsigned short* wdk_p  = wo_p + 131072;
    unsigned short* wdv_p  = wdk_p + 32768;
    float* bias3 = (float*)(wdv_p + 32768);

    hipMemsetAsync(agg, 0, (size_t)NN * H * sizeof(float), stream);
    k_prep<<<242, 256, 0, stream>>>(Wq, Wk, Wv, Wo, g, b, bq, bk, bv, Wdk, Wdv,
                                    wqkv_p, wo_p, wdk_p, wdv_p, bias3, hist);
    k_hist<<<EE / 256, 256, 0, stream>>>(ei, hist);
    k_ln_qkv<<<(NN + 15) / 16, 64, 0, stream>>>(x, wqkv_p, bias3, q16, k16, v16);
    k_scan1<<<NB, 256, 0, stream>>>(hist, cur, bsum);
    k_scan2<<<1, 128, 0, stream>>>(bsum);
    k_scatter<<<EE / 256, 256, 0, stream>>>(ei, cur, bsum, perm);
    k_edge<<<EE / 64, 256, 0, stream>>>(q16, k16, v16, ei, ew, ea, wdk_p, bdk, wdv_p, bdv, perm, agg);
    k_out<<<(NN + 15) / 16, 64, 0, stream>>>(agg, wo_p, bo, x, (float*)d_out);
}

// Round 8
// 635.271 us; speedup vs baseline: 1.2545x; 1.2545x over previous
//
#include <hip/hip_runtime.h>
#include <math.h>

#define NN 20000
#define H 256
#define R 64
#define EE 320000
#define LN_EPS 1e-5f
#define NB 79   // ceil(NN/256)

using short8  = __attribute__((ext_vector_type(8))) short;
using ushort8 = __attribute__((ext_vector_type(8))) unsigned short;
using f32x4   = __attribute__((ext_vector_type(4))) float;

typedef __attribute__((address_space(3))) unsigned int lds_uint;
typedef const __attribute__((address_space(1))) unsigned int glb_uint;

__device__ __forceinline__ float silu_f(float x) {
    return x * __builtin_amdgcn_rcpf(1.0f + __expf(-x));
}

// round-to-nearest-even fp32 -> bf16 (as ushort)
__device__ __forceinline__ unsigned short f2bf(float f) {
    unsigned u = __float_as_uint(f);
    u += 0x7fff + ((u >> 16) & 1);
    return (unsigned short)(u >> 16);
}
__device__ __forceinline__ float bf2f(unsigned short s) {
    return __uint_as_float(((unsigned)s) << 16);
}
// f32 <-> f16 (RNE) via v_cvt
__device__ __forceinline__ unsigned short f2h(float f) {
    unsigned r;
    asm("v_cvt_f16_f32 %0, %1" : "=v"(r) : "v"(f));
    return (unsigned short)r;
}
__device__ __forceinline__ float h2f(unsigned short h) {
    float f;
    asm("v_cvt_f32_f16 %0, %1" : "=v"(f) : "v"((unsigned)h));
    return f;
}

// XOR-swizzled LDS index for [row][64] short arrays (bf16 fragments)
__device__ __forceinline__ int sw_idx(int row, int col) {
    return row * 64 + ((((col >> 3) ^ (row & 7)) << 3) | (col & 7));
}
// dks f16 [64][256]: xor col bits[5:4] by row bits[3:2]; 4-element runs at
// col%4==0 stay contiguous (XOR only touches bits >= 4).
__device__ __forceinline__ int dh_idx(int row, int col) {
    return row * 256 + (col ^ (((row >> 2) & 3) << 4));
}

// ---------------------------------------------------------------------------
// Combined prep (one launch, 242 blocks)
// ---------------------------------------------------------------------------
__global__ __launch_bounds__(256) void k_prep(
    const float* __restrict__ Wq, const float* __restrict__ Wk,
    const float* __restrict__ Wv, const float* __restrict__ Wo,
    const float* __restrict__ g,  const float* __restrict__ b,
    const float* __restrict__ bq, const float* __restrict__ bk, const float* __restrict__ bv,
    const float* __restrict__ Wdk, const float* __restrict__ Wdv,
    unsigned short* __restrict__ wqkv_p, unsigned short* __restrict__ wo_p,
    unsigned short* __restrict__ wdk_p,  unsigned short* __restrict__ wdv_p,
    float* __restrict__ bias3, int* __restrict__ hist)
{
    const int bid = blockIdx.x, t = threadIdx.x;
    if (bid < 128) {
        const int mat = bid >> 5;
        const float* W = mat == 0 ? Wq : (mat == 1 ? Wk : (mat == 2 ? Wv : Wo));
        unsigned short* out = (mat < 3) ? wqkv_p + (size_t)mat * 131072 : wo_p;
        const int fold = mat < 3;
        const int flat = (bid & 31) * 256 + t;           // [0, 8192)
        const int tile = flat >> 9;
        const int rem  = flat & 511;
        const int ks   = rem >> 6;
        const int lane = rem & 63;
        const int nl = lane & 15, quad = lane >> 4;
        const int h  = tile * 16 + nl;
        const int c0 = ks * 32 + quad * 8;
        short8 hi8, lo8;
        #pragma unroll
        for (int j = 0; j < 8; ++j) {
            float wv = W[(size_t)h * 256 + c0 + j];
            if (fold) wv *= g[c0 + j];
            const unsigned short hh = f2bf(wv);
            hi8[j] = (short)hh;
            lo8[j] = (short)f2bf(wv - bf2f(hh));
        }
        unsigned short* ob = out + ((size_t)(tile * 8 + ks)) * 1024;
        *(short8*)&ob[lane * 8] = hi8;
        *(short8*)&ob[512 + lane * 8] = lo8;
    } else if (bid < 160) {
        const int flat = (bid - 128) * 256 + t;          // [0, 8192)
        const int mat  = flat >> 12;
        const int rem  = flat & 4095;
        const int hh   = rem >> 11;
        const int r2   = rem & 2047;
        const int row  = r2 >> 4;
        const int col4 = (r2 & 15) * 4;
        const float* W = mat == 0 ? Wdk : Wdv;
        unsigned short* out = (mat == 0 ? wdk_p : wdv_p) + hh * 16384;
        const float4 w4 = *(const float4*)(W + (size_t)(hh * 128 + row) * 64 + col4);
        const unsigned short h0 = f2bf(w4.x), h1 = f2bf(w4.y), h2 = f2bf(w4.z), h3 = f2bf(w4.w);
        ushort4 hi4 = {h0, h1, h2, h3};
        ushort4 lo4 = {f2bf(w4.x - bf2f(h0)), f2bf(w4.y - bf2f(h1)),
                       f2bf(w4.z - bf2f(h2)), f2bf(w4.w - bf2f(h3))};
        const int di = sw_idx(row, col4);
        *(ushort4*)&out[di] = hi4;
        *(ushort4*)&out[8192 + di] = lo4;
    } else if (bid < 163) {
        const int mat = bid - 160, h = t;
        const float* W  = mat == 0 ? Wq : (mat == 1 ? Wk : Wv);
        const float* bb = mat == 0 ? bq : (mat == 1 ? bk : bv);
        float s = 0.f;
        const float* wr = W + (size_t)h * 256;
        for (int c = 0; c < 256; c += 4) {
            const float4 w4 = *(const float4*)(wr + c);
            const float4 b4 = *(const float4*)(b + c);
            s += w4.x * b4.x + w4.y * b4.y + w4.z * b4.z + w4.w * b4.w;
        }
        bias3[mat * 256 + h] = bb[h] + s;
    } else {
        const int i = (bid - 163) * 256 + t;
        if (i < NN) hist[i] = 0;
    }
}

// ---------------------------------------------------------------------------
// K1: LayerNorm + QKV via split-bf16 MFMA. 16 nodes per 64-thread block.
// q/k/v stored f16 (halves k_edge gather bytes + own store bytes).
// ---------------------------------------------------------------------------
__global__ __launch_bounds__(64, 2) void k_ln_qkv(
    const float* __restrict__ x,
    const unsigned short* __restrict__ wqkv_p, const float* __restrict__ bias3,
    unsigned short* __restrict__ q, unsigned short* __restrict__ k,
    unsigned short* __restrict__ v)
{
    const int t = threadIdx.x;
    const int lane = t & 63;
    const int nl = lane & 15, quad = lane >> 4;
    const int nbase = blockIdx.x * 16;
    const int node = nbase + nl;
    const bool nv = node < NN;

    float xv[64];
    float sum = 0.f, sq = 0.f;
    {
        const float* xp = x + (size_t)node * H + quad * 8;
        #pragma unroll
        for (int ks = 0; ks < 8; ++ks) {
            float4 x0 = {0.f,0.f,0.f,0.f}, x1 = {0.f,0.f,0.f,0.f};
            if (nv) {
                x0 = *(const float4*)(xp + ks * 32);
                x1 = *(const float4*)(xp + ks * 32 + 4);
            }
            xv[ks*8+0]=x0.x; xv[ks*8+1]=x0.y; xv[ks*8+2]=x0.z; xv[ks*8+3]=x0.w;
            xv[ks*8+4]=x1.x; xv[ks*8+5]=x1.y; xv[ks*8+6]=x1.z; xv[ks*8+7]=x1.w;
            sum += x0.x+x0.y+x0.z+x0.w + x1.x+x1.y+x1.z+x1.w;
            sq  += x0.x*x0.x+x0.y*x0.y+x0.z*x0.z+x0.w*x0.w
                 + x1.x*x1.x+x1.y*x1.y+x1.z*x1.z+x1.w*x1.w;
        }
    }
    sum += __shfl_xor(sum, 16); sum += __shfl_xor(sum, 32);
    sq  += __shfl_xor(sq, 16);  sq  += __shfl_xor(sq, 32);
    const float mu  = sum * (1.0f / H);
    const float var = sq * (1.0f / H) - mu * mu;
    const float rs  = rsqrtf(var + LN_EPS);

    short8 a_hi[8], a_lo[8];
    #pragma unroll
    for (int ks = 0; ks < 8; ++ks) {
        #pragma unroll
        for (int j = 0; j < 8; ++j) {
            const float z = (xv[ks*8+j] - mu) * rs;
            const unsigned short hh = f2bf(z);
            a_hi[ks][j] = (short)hh;
            a_lo[ks][j] = (short)f2bf(z - bf2f(hh));
        }
    }

    for (int mat = 0; mat < 3; ++mat) {
        unsigned short* outp = mat == 0 ? q : (mat == 1 ? k : v);
        const float* bp = bias3 + mat * 256;
        const unsigned short* wb = wqkv_p + (size_t)mat * 131072 + lane * 8;
        for (int tile = 0; tile < 16; ++tile) {
            const unsigned short* gb = wb + (size_t)tile * 8192;
            const float bbv = bp[tile * 16 + nl];
            f32x4 acc = {bbv, bbv, bbv, bbv};
            #pragma unroll
            for (int ks = 0; ks < 8; ++ks) {
                const short8 b_hi = *(const short8*)(gb + ks * 1024);
                const short8 b_lo = *(const short8*)(gb + ks * 1024 + 512);
                acc = __builtin_amdgcn_mfma_f32_16x16x32_bf16(a_hi[ks], b_hi, acc, 0, 0, 0);
                acc = __builtin_amdgcn_mfma_f32_16x16x32_bf16(a_lo[ks], b_hi, acc, 0, 0, 0);
                acc = __builtin_amdgcn_mfma_f32_16x16x32_bf16(a_hi[ks], b_lo, acc, 0, 0, 0);
            }
            #pragma unroll
            for (int r = 0; r < 4; ++r) {
                const int onode = nbase + quad * 4 + r;
                if (onode < NN)
                    outp[(size_t)onode * H + tile * 16 + nl] = f2h(acc[r]);
            }
        }
    }
}

// ---------------------------------------------------------------------------
// Counting sort of edges by dst: hist -> scan -> scatter
// ---------------------------------------------------------------------------
__global__ __launch_bounds__(256) void k_hist(const int* __restrict__ ei, int* __restrict__ hist) {
    int e = blockIdx.x * 256 + threadIdx.x;
    if (e < EE) atomicAdd(&hist[ei[EE + e]], 1);
}

__global__ __launch_bounds__(256) void k_scan1(const int* __restrict__ hist,
                                               int* __restrict__ cursor, int* __restrict__ bsum) {
    const int t = threadIdx.x, i = blockIdx.x * 256 + t;
    const int lane = t & 63, w = t >> 6;
    const int v = (i < NN) ? hist[i] : 0;
    int incl = v;
    #pragma unroll
    for (int off = 1; off < 64; off <<= 1) {
        int u = __shfl_up(incl, off);
        if (lane >= off) incl += u;
    }
    __shared__ int ws[4];
    if (lane == 63) ws[w] = incl;
    __syncthreads();
    int base = 0;
    #pragma unroll
    for (int j = 0; j < 4; ++j) if (j < w) base += ws[j];
    if (i < NN) cursor[i] = base + incl - v;
    if (t == 255) bsum[blockIdx.x] = base + incl;
}

__global__ __launch_bounds__(128) void k_scan2(int* __restrict__ bsum) {
    __shared__ int buf[128];
    const int t = threadIdx.x;
    const int v = (t < NB) ? bsum[t] : 0;
    buf[t] = v;
    __syncthreads();
    #pragma unroll
    for (int off = 1; off < 128; off <<= 1) {
        int add = (t >= off) ? buf[t - off] : 0;
        __syncthreads();
        buf[t] += add;
        __syncthreads();
    }
    if (t < NB) bsum[t] = buf[t] - v;
}

// scatter also materializes sorted src/dst/ew streams: k_edge's serial head
// becomes one load deep (was perm -> ei -> row, 3 dependent levels).
__global__ __launch_bounds__(256) void k_scatter(const int* __restrict__ ei,
                                                 const float* __restrict__ ew,
                                                 int* __restrict__ cursor,
                                                 const int* __restrict__ bsum,
                                                 int* __restrict__ perm,
                                                 int* __restrict__ srcs,
                                                 int* __restrict__ dsts,
                                                 float* __restrict__ ews) {
    int e = blockIdx.x * 256 + threadIdx.x;
    if (e < EE) {
        int s = ei[e];
        int d = ei[EE + e];
        int pos = atomicAdd(&cursor[d], 1) + bsum[d >> 8];
        perm[pos] = e;
        srcs[pos] = s;
        dsts[pos] = d;
        ews[pos] = ew[e];
    }
}

// ---------------------------------------------------------------------------
// K2: round-6 structure (merged halves, 2 gather phases -- the only proven
// win) + f16 q/k/v gathers (round-7's FETCH -160MB, kept) WITHOUT the
// register prefetch (round-7's scratch-spill regression, dropped: WRITE 2x
// at VGPR 120 was spill writeback).
// ---------------------------------------------------------------------------
__global__ __launch_bounds__(256, 2) void k_edge(
    const unsigned short* __restrict__ q16, const unsigned short* __restrict__ k16,
    const unsigned short* __restrict__ v16,
    const float* __restrict__ ea,
    const unsigned short* __restrict__ wdk_p, const float* __restrict__ bdk,
    const unsigned short* __restrict__ wdv_p, const float* __restrict__ bdv,
    const int* __restrict__ perm, const int* __restrict__ srcs,
    const int* __restrict__ dsts, const float* __restrict__ ews,
    float* __restrict__ agg)
{
    __shared__ __align__(16) unsigned short w_region[2 * 128 * 64];  // 32 KB hi|lo
    __shared__ __align__(16) unsigned short dks_h[64 * 256];         // 32 KB f16, both halves
    __shared__ float attn_s[64];
    __shared__ int src_s[64], dst_s[64];

    const unsigned short* w_hi_s = w_region;
    const unsigned short* w_lo_s = w_region + 128 * 64;

    const int t    = threadIdx.x;
    const int bi   = blockIdx.x;
    const int eb   = ((bi & 7) * 625 + (bi >> 3)) * 64;   // XCD-contiguous chunks
    const int lane = t & 63, wave = t >> 6;
    const int nl   = lane & 15, quad = lane >> 4;
    const int estrip = wave * 16;
    const int tx = t & 31, ty = t >> 5;
    const int h0 = tx * 4, e0 = ty * 8;

    #define STAGE(PTR)                                                                \
    {                                                                                 \
        const ushort8* sp = (const ushort8*)(PTR) + t;                                \
        ushort8* dpw = (ushort8*)w_region + (t & 192);                                \
        _Pragma("unroll")                                                             \
        for (int c = 0; c < 8; ++c)                                                   \
            __builtin_amdgcn_global_load_lds((glb_uint*)(sp + c * 256),               \
                                             (lds_uint*)(dpw + c * 256), 16, 0, 0);   \
    }

    #define MFMA_TO_DKS(BIAS, HALF)                                                   \
    {                                                                                 \
        f32x4 accA[8];                                                                \
        _Pragma("unroll")                                                             \
        for (int tt = 0; tt < 8; ++tt) {                                              \
            const int wrow = tt * 16 + nl;                                            \
            short8 b_hi[2], b_lo[2];                                                  \
            _Pragma("unroll")                                                         \
            for (int ks = 0; ks < 2; ++ks) {                                          \
                const int idx = wrow * 64 + ((((ks * 4 + quad) ^ (nl & 7)) << 3));    \
                b_hi[ks] = *(const short8*)&w_hi_s[idx];                              \
                b_lo[ks] = *(const short8*)&w_lo_s[idx];                              \
            }                                                                         \
            const float bb = (BIAS)[(HALF) * 128 + tt * 16 + nl];                     \
            f32x4 acc = {bb, bb, bb, bb};                                             \
            _Pragma("unroll")                                                         \
            for (int ks = 0; ks < 2; ++ks) {                                          \
                acc = __builtin_amdgcn_mfma_f32_16x16x32_bf16(a_hi[ks], b_hi[ks], acc, 0, 0, 0); \
                acc = __builtin_amdgcn_mfma_f32_16x16x32_bf16(a_lo[ks], b_hi[ks], acc, 0, 0, 0); \
                acc = __builtin_amdgcn_mfma_f32_16x16x32_bf16(a_hi[ks], b_lo[ks], acc, 0, 0, 0); \
            }                                                                         \
            accA[tt] = acc;                                                           \
        }                                                                             \
        __syncthreads();  /* all waves done reading w_region */                       \
        _Pragma("unroll")                                                             \
        for (int tt = 0; tt < 8; ++tt)                                                \
            _Pragma("unroll")                                                         \
            for (int r = 0; r < 4; ++r)                                               \
                dks_h[dh_idx(estrip + quad * 4 + r, (HALF) * 128 + tt * 16 + nl)] =   \
                    f2h(silu_f(accA[tt][r]));                                         \
    }

    // stage image 0 (wdk half 0)
    STAGE(wdk_p);

    if (t < 64) {
        src_s[t] = srcs[eb + t];
        dst_s[t] = dsts[eb + t];
        attn_s[t] = 0.f;
    }

    // ea A-fragments straight from global, in-register hi/lo split
    short8 a_hi[2], a_lo[2];
    {
        const int e = perm[eb + estrip + nl];
        const float* ap = ea + (size_t)e * R + quad * 8;
        #pragma unroll
        for (int ks = 0; ks < 2; ++ks) {
            const f32x4 x0 = *(const f32x4*)(ap + ks * 32);
            const f32x4 x1 = *(const f32x4*)(ap + ks * 32 + 4);
            const float zz[8] = {x0[0], x0[1], x0[2], x0[3], x1[0], x1[1], x1[2], x1[3]};
            #pragma unroll
            for (int j = 0; j < 8; ++j) {
                const unsigned short hv = f2bf(zz[j]);
                a_hi[ks][j] = (short)hv;
                a_lo[ks][j] = (short)f2bf(zz[j] - bf2f(hv));
            }
        }
    }
    __syncthreads();   // image dk.h0 landed; src/dst visible

    // ---- dk half 0 ---- (manual: STAGE sits between barrier and dks write)
    {
        f32x4 accA[8];
        #pragma unroll
        for (int tt = 0; tt < 8; ++tt) {
            const int wrow = tt * 16 + nl;
            short8 b_hi[2], b_lo[2];
            #pragma unroll
            for (int ks = 0; ks < 2; ++ks) {
                const int idx = wrow * 64 + ((((ks * 4 + quad) ^ (nl & 7)) << 3));
                b_hi[ks] = *(const short8*)&w_hi_s[idx];
                b_lo[ks] = *(const short8*)&w_lo_s[idx];
            }
            const float bb = bdk[tt * 16 + nl];
            f32x4 acc = {bb, bb, bb, bb};
            #pragma unroll
            for (int ks = 0; ks < 2; ++ks) {
                acc = __builtin_amdgcn_mfma_f32_16x16x32_bf16(a_hi[ks], b_hi[ks], acc, 0, 0, 0);
                acc = __builtin_amdgcn_mfma_f32_16x16x32_bf16(a_lo[ks], b_hi[ks], acc, 0, 0, 0);
                acc = __builtin_amdgcn_mfma_f32_16x16x32_bf16(a_hi[ks], b_lo[ks], acc, 0, 0, 0);
            }
            accA[tt] = acc;
        }
        __syncthreads();           // w_region free
        STAGE(wdk_p + 16384);      // dk half 1
        #pragma unroll
        for (int tt = 0; tt < 8; ++tt)
            #pragma unroll
            for (int r = 0; r < 4; ++r)
                dks_h[dh_idx(estrip + quad * 4 + r, tt * 16 + nl)] =
                    f2h(silu_f(accA[tt][r]));
    }
    __syncthreads();               // dk.h1 landed
    MFMA_TO_DKS(bdk, 1);
    STAGE(wdv_p);                  // dv half 0 -- lands during pass A

    // ---- pass A: single gather phase, f16 q/k, full 256-wide rows ----
    {
        float qv[8];
        int pd = -1;
        #pragma unroll
        for (int i = 0; i < 8; ++i) {
            const int d = dst_s[e0 + i], s = src_s[e0 + i];
            if (d != pd) {
                const ushort4 q0 = *(const ushort4*)(q16 + (size_t)d * H + h0);
                const ushort4 q1 = *(const ushort4*)(q16 + (size_t)d * H + 128 + h0);
                qv[0] = h2f(q0.x); qv[1] = h2f(q0.y); qv[2] = h2f(q0.z); qv[3] = h2f(q0.w);
                qv[4] = h2f(q1.x); qv[5] = h2f(q1.y); qv[6] = h2f(q1.z); qv[7] = h2f(q1.w);
                pd = d;
            }
            const ushort4 k0 = *(const ushort4*)(k16 + (size_t)s * H + h0);
            const ushort4 k1 = *(const ushort4*)(k16 + (size_t)s * H + 128 + h0);
            const ushort4 d40 = *(const ushort4*)&dks_h[dh_idx(e0 + i, h0)];
            const ushort4 d41 = *(const ushort4*)&dks_h[dh_idx(e0 + i, 128 + h0)];
            float part = qv[0] * h2f(k0.x) * h2f(d40.x) + qv[1] * h2f(k0.y) * h2f(d40.y)
                       + qv[2] * h2f(k0.z) * h2f(d40.z) + qv[3] * h2f(k0.w) * h2f(d40.w)
                       + qv[4] * h2f(k1.x) * h2f(d41.x) + qv[5] * h2f(k1.y) * h2f(d41.y)
                       + qv[6] * h2f(k1.z) * h2f(d41.z) + qv[7] * h2f(k1.w) * h2f(d41.w);
            #pragma unroll
            for (int off = 16; off; off >>= 1) part += __shfl_xor(part, off);
            if (tx == 0) attn_s[e0 + i] += part;
        }
    }
    __syncthreads();               // pass A complete everywhere; dv.h0 landed

    // attn finalize (wave 0); published by the next macro's internal barrier
    if (t < 64) {
        const float rr = ews[eb + t];
        const float cut = (rr < 5.0f) ? 0.5f * (__cosf(rr * 0.6283185307f) + 1.0f) : 0.0f;
        attn_s[t] = silu_f(attn_s[t]) * cut;
    }

    MFMA_TO_DKS(bdv, 0);
    STAGE(wdv_p + 16384);          // dv half 1
    __syncthreads();               // dv.h1 landed
    MFMA_TO_DKS(bdv, 1);

    // ---- pass B: single gather phase, f16 v, run-flush row-walk ----
    {
        float4 m0 = {0.f,0.f,0.f,0.f}, m1 = {0.f,0.f,0.f,0.f};
        int cur_d = -1;
        #pragma unroll
        for (int i = 0; i < 8; ++i) {
            const int d = dst_s[e0 + i], s = src_s[e0 + i];
            const float a = attn_s[e0 + i];
            const ushort4 v0 = *(const ushort4*)(v16 + (size_t)s * H + h0);
            const ushort4 v1 = *(const ushort4*)(v16 + (size_t)s * H + 128 + h0);
            const ushort4 d40 = *(const ushort4*)&dks_h[dh_idx(e0 + i, h0)];
            const ushort4 d41 = *(const ushort4*)&dks_h[dh_idx(e0 + i, 128 + h0)];
            const float w0x = h2f(v0.x) * h2f(d40.x) * a, w0y = h2f(v0.y) * h2f(d40.y) * a;
            const float w0z = h2f(v0.z) * h2f(d40.z) * a, w0w = h2f(v0.w) * h2f(d40.w) * a;
            const float w1x = h2f(v1.x) * h2f(d41.x) * a, w1y = h2f(v1.y) * h2f(d41.y) * a;
            const float w1z = h2f(v1.z) * h2f(d41.z) * a, w1w = h2f(v1.w) * h2f(d41.w) * a;
            if (d != cur_d) {
                if (cur_d >= 0) {
                    float* dp = agg + (size_t)cur_d * H;
                    atomicAdd(dp + h0 + 0, m0.x); atomicAdd(dp + h0 + 1, m0.y);
                    atomicAdd(dp + h0 + 2, m0.z); atomicAdd(dp + h0 + 3, m0.w);
                    atomicAdd(dp + 128 + h0 + 0, m1.x); atomicAdd(dp + 128 + h0 + 1, m1.y);
                    atomicAdd(dp + 128 + h0 + 2, m1.z); atomicAdd(dp + 128 + h0 + 3, m1.w);
                }
                m0.x = w0x; m0.y = w0y; m0.z = w0z; m0.w = w0w;
                m1.x = w1x; m1.y = w1y; m1.z = w1z; m1.w = w1w;
                cur_d = d;
            } else {
                m0.x += w0x; m0.y += w0y; m0.z += w0z; m0.w += w0w;
                m1.x += w1x; m1.y += w1y; m1.z += w1z; m1.w += w1w;
            }
        }
        {
            float* dp = agg + (size_t)cur_d * H;
            atomicAdd(dp + h0 + 0, m0.x); atomicAdd(dp + h0 + 1, m0.y);
            atomicAdd(dp + h0 + 2, m0.z); atomicAdd(dp + h0 + 3, m0.w);
            atomicAdd(dp + 128 + h0 + 0, m1.x); atomicAdd(dp + 128 + h0 + 1, m1.y);
            atomicAdd(dp + 128 + h0 + 2, m1.z); atomicAdd(dp + 128 + h0 + 3, m1.w);
        }
    }
    #undef MFMA_TO_DKS
    #undef STAGE
}

// ---------------------------------------------------------------------------
// K3: out = x + agg @ Wo'^T + bo via split-bf16 MFMA. 16 nodes / 64-thr block.
// ---------------------------------------------------------------------------
__global__ __launch_bounds__(64, 2) void k_out(
    const float* __restrict__ aggm, const unsigned short* __restrict__ wo_p,
    const float* __restrict__ bo, const float* __restrict__ x, float* __restrict__ out)
{
    const int t = threadIdx.x;
    const int lane = t & 63;
    const int nl = lane & 15, quad = lane >> 4;
    const int nbase = blockIdx.x * 16;
    const int node = nbase + nl;
    const bool nv = node < NN;

    short8 a_hi[8], a_lo[8];
    {
        const float* ap = aggm + (size_t)node * H + quad * 8;
        #pragma unroll
        for (int ks = 0; ks < 8; ++ks) {
            float4 x0 = {0.f,0.f,0.f,0.f}, x1 = {0.f,0.f,0.f,0.f};
            if (nv) { x0 = *(const float4*)(ap + ks * 32); x1 = *(const float4*)(ap + ks * 32 + 4); }
            const float zz[8] = {x0.x,x0.y,x0.z,x0.w,x1.x,x1.y,x1.z,x1.w};
            #pragma unroll
            for (int j = 0; j < 8; ++j) {
                const unsigned short hh = f2bf(zz[j]);
                a_hi[ks][j] = (short)hh;
                a_lo[ks][j] = (short)f2bf(zz[j] - bf2f(hh));
            }
        }
    }
    for (int tile = 0; tile < 16; ++tile) {
        const unsigned short* gb = wo_p + (size_t)tile * 8192 + lane * 8;
        const float bbv = bo[tile * 16 + nl];
        f32x4 acc = {bbv, bbv, bbv, bbv};
        #pragma unroll
        for (int ks = 0; ks < 8; ++ks) {
            const short8 b_hi = *(const short8*)(gb + ks * 1024);
            const short8 b_lo = *(const short8*)(gb + ks * 1024 + 512);
            acc = __builtin_amdgcn_mfma_f32_16x16x32_bf16(a_hi[ks], b_hi, acc, 0, 0, 0);
            acc = __builtin_amdgcn_mfma_f32_16x16x32_bf16(a_lo[ks], b_hi, acc, 0, 0, 0);
            acc = __builtin_amdgcn_mfma_f32_16x16x32_bf16(a_hi[ks], b_lo, acc, 0, 0, 0);
        }
        #pragma unroll
        for (int r = 0; r < 4; ++r) {
            const int onode = nbase + quad * 4 + r;
            if (onode < NN) {
                const size_t oi = (size_t)onode * H + tile * 16 + nl;
                out[oi] = x[oi] + acc[r];
            }
        }
    }
}

extern "C" void kernel_launch(void* const* d_in, const int* in_sizes, int n_in,
                              void* d_out, int out_size, void* d_ws, size_t ws_size,
                              hipStream_t stream) {
    const float* x   = (const float*)d_in[0];
    const int*   ei  = (const int*)d_in[1];
    const float* ew  = (const float*)d_in[2];
    const float* ea  = (const float*)d_in[3];
    const float* g   = (const float*)d_in[4];
    const float* b   = (const float*)d_in[5];
    const float* Wq  = (const float*)d_in[6];  const float* bq  = (const float*)d_in[7];
    const float* Wk  = (const float*)d_in[8];  const float* bk  = (const float*)d_in[9];
    const float* Wv  = (const float*)d_in[10]; const float* bv  = (const float*)d_in[11];
    const float* Wo  = (const float*)d_in[12]; const float* bo  = (const float*)d_in[13];
    const float* Wdk = (const float*)d_in[14]; const float* bdk = (const float*)d_in[15];
    const float* Wdv = (const float*)d_in[16]; const float* bdv = (const float*)d_in[17];

    unsigned short* q16 = (unsigned short*)d_ws;
    unsigned short* k16 = q16 + (size_t)NN * H;
    unsigned short* v16 = k16 + (size_t)NN * H;
    float* agg  = (float*)(v16 + (size_t)NN * H);
    int*   hist = (int*)(agg + (size_t)NN * H);
    int*   cur  = hist + NN;
    int*   bsum = cur + NN;
    int*   perm = bsum + 128;
    int*   srcs = perm + EE;
    int*   dsts = srcs + EE;
    float* ews  = (float*)(dsts + EE);
    unsigned short* wqkv_p = (unsigned short*)(ews + EE);
    unsigned short* wo_p   = wqkv_p + 393216;
    unsigned short* wdk_p  = wo_p + 131072;
    unsigned short* wdv_p  = wdk_p + 32768;
    float* bias3 = (float*)(wdv_p + 32768);

    hipMemsetAsync(agg, 0, (size_t)NN * H * sizeof(float), stream);
    k_prep<<<242, 256, 0, stream>>>(Wq, Wk, Wv, Wo, g, b, bq, bk, bv, Wdk, Wdv,
                                    wqkv_p, wo_p, wdk_p, wdv_p, bias3, hist);
    k_hist<<<EE / 256, 256, 0, stream>>>(ei, hist);
    k_ln_qkv<<<(NN + 15) / 16, 64, 0, stream>>>(x, wqkv_p, bias3, q16, k16, v16);
    k_scan1<<<NB, 256, 0, stream>>>(hist, cur, bsum);
    k_scan2<<<1, 128, 0, stream>>>(bsum);
    k_scatter<<<EE / 256, 256, 0, stream>>>(ei, ew, cur, bsum, perm, srcs, dsts, ews);
    k_edge<<<EE / 64, 256, 0, stream>>>(q16, k16, v16, ea, wdk_p, bdk, wdv_p, bdv,
                                        perm, srcs, dsts, ews, agg);
    k_out<<<(NN + 15) / 16, 64, 0, stream>>>(agg, wo_p, bo, x, (float*)d_out);
}

// Round 9
// 628.008 us; speedup vs baseline: 1.2690x; 1.0116x over previous
//
#include <hip/hip_runtime.h>
#include <math.h>

#define NN 20000
#define H 256
#define R 64
#define EE 320000
#define LN_EPS 1e-5f
#define NB 79   // ceil(NN/256)

using short8  = __attribute__((ext_vector_type(8))) short;
using ushort8 = __attribute__((ext_vector_type(8))) unsigned short;
using f32x4   = __attribute__((ext_vector_type(4))) float;

__device__ __forceinline__ float silu_f(float x) {
    return x * __builtin_amdgcn_rcpf(1.0f + __expf(-x));
}

// round-to-nearest-even fp32 -> bf16 (as ushort)
__device__ __forceinline__ unsigned short f2bf(float f) {
    unsigned u = __float_as_uint(f);
    u += 0x7fff + ((u >> 16) & 1);
    return (unsigned short)(u >> 16);
}
__device__ __forceinline__ float bf2f(unsigned short s) {
    return __uint_as_float(((unsigned)s) << 16);
}
// f32 <-> f16 (RNE) via v_cvt
__device__ __forceinline__ unsigned short f2h(float f) {
    unsigned r;
    asm("v_cvt_f16_f32 %0, %1" : "=v"(r) : "v"(f));
    return (unsigned short)r;
}
__device__ __forceinline__ float h2f(unsigned short h) {
    float f;
    asm("v_cvt_f32_f16 %0, %1" : "=v"(f) : "v"((unsigned)h));
    return f;
}

// dks f16 [16][256] per-wave slice: xor col bits[5:4] by row bits[3:2]
// (local row: (row>>2)&3 == writing lane's quad) -> conflict-free b16 writes;
// 4/8-element runs at col%4==0 stay contiguous (XOR touches only bits >= 4).
__device__ __forceinline__ int dh_idx(int row, int col) {
    return row * 256 + (col ^ (((row >> 2) & 3) << 4));
}

// ---------------------------------------------------------------------------
// Combined prep (one launch, 226 blocks):
//  [0,128):   pack Wq/Wk/Wv (g folded) + Wo into MFMA B-fragment order
//  [128,144): pack Wdk/Wdv fragment-linear (same per-lane-contiguous layout
//             as wqkv; k_edge reads fragments DIRECT from global, no LDS)
//  [144,147): adjusted QKV biases
//  [147,226): zero hist
// ---------------------------------------------------------------------------
__global__ __launch_bounds__(256) void k_prep(
    const float* __restrict__ Wq, const float* __restrict__ Wk,
    const float* __restrict__ Wv, const float* __restrict__ Wo,
    const float* __restrict__ g,  const float* __restrict__ b,
    const float* __restrict__ bq, const float* __restrict__ bk, const float* __restrict__ bv,
    const float* __restrict__ Wdk, const float* __restrict__ Wdv,
    unsigned short* __restrict__ wqkv_p, unsigned short* __restrict__ wo_p,
    unsigned short* __restrict__ wdk_p,  unsigned short* __restrict__ wdv_p,
    float* __restrict__ bias3, int* __restrict__ hist)
{
    const int bid = blockIdx.x, t = threadIdx.x;
    if (bid < 128) {
        const int mat = bid >> 5;
        const float* W = mat == 0 ? Wq : (mat == 1 ? Wk : (mat == 2 ? Wv : Wo));
        unsigned short* out = (mat < 3) ? wqkv_p + (size_t)mat * 131072 : wo_p;
        const int fold = mat < 3;
        const int flat = (bid & 31) * 256 + t;           // [0, 8192)
        const int tile = flat >> 9;
        const int rem  = flat & 511;
        const int ks   = rem >> 6;
        const int lane = rem & 63;
        const int nl = lane & 15, quad = lane >> 4;
        const int h  = tile * 16 + nl;
        const int c0 = ks * 32 + quad * 8;
        short8 hi8, lo8;
        #pragma unroll
        for (int j = 0; j < 8; ++j) {
            float wv = W[(size_t)h * 256 + c0 + j];
            if (fold) wv *= g[c0 + j];
            const unsigned short hh = f2bf(wv);
            hi8[j] = (short)hh;
            lo8[j] = (short)f2bf(wv - bf2f(hh));
        }
        unsigned short* ob = out + ((size_t)(tile * 8 + ks)) * 1024;
        *(short8*)&ob[lane * 8] = hi8;
        *(short8*)&ob[512 + lane * 8] = lo8;
    } else if (bid < 144) {
        // dk/dv fragment-linear pack: value = W[hh*128 + tile*16+nl][ks*32+quad*8+j]
        // hi at img[(tile*2+ks)*1024 + lane*8], lo at +512. img = half base.
        const int flat = (bid - 128) * 256 + t;          // [0, 4096)
        const int mat  = flat >> 11;
        const int rem  = flat & 2047;
        const int hh   = rem >> 10;
        const int r2   = rem & 1023;
        const int tile = r2 >> 7;
        const int r3   = r2 & 127;
        const int ks   = r3 >> 6;
        const int lane = r3 & 63;
        const int nl = lane & 15, quad = lane >> 4;
        const float* W = mat == 0 ? Wdk : Wdv;
        unsigned short* out = (mat == 0 ? wdk_p : wdv_p)
                            + hh * 16384 + (tile * 2 + ks) * 1024 + lane * 8;
        const float* wr = W + (size_t)(hh * 128 + tile * 16 + nl) * 64 + ks * 32 + quad * 8;
        const float4 w0 = *(const float4*)wr;
        const float4 w1 = *(const float4*)(wr + 4);
        const float zz[8] = {w0.x, w0.y, w0.z, w0.w, w1.x, w1.y, w1.z, w1.w};
        short8 hi8, lo8;
        #pragma unroll
        for (int j = 0; j < 8; ++j) {
            const unsigned short hv = f2bf(zz[j]);
            hi8[j] = (short)hv;
            lo8[j] = (short)f2bf(zz[j] - bf2f(hv));
        }
        *(short8*)out = hi8;
        *(short8*)(out + 512) = lo8;
    } else if (bid < 147) {
        const int mat = bid - 144, h = t;
        const float* W  = mat == 0 ? Wq : (mat == 1 ? Wk : Wv);
        const float* bb = mat == 0 ? bq : (mat == 1 ? bk : bv);
        float s = 0.f;
        const float* wr = W + (size_t)h * 256;
        for (int c = 0; c < 256; c += 4) {
            const float4 w4 = *(const float4*)(wr + c);
            const float4 b4 = *(const float4*)(b + c);
            s += w4.x * b4.x + w4.y * b4.y + w4.z * b4.z + w4.w * b4.w;
        }
        bias3[mat * 256 + h] = bb[h] + s;
    } else {
        const int i = (bid - 147) * 256 + t;
        if (i < NN) hist[i] = 0;
    }
}

// ---------------------------------------------------------------------------
// K1: LayerNorm + QKV via split-bf16 MFMA. 16 nodes per 64-thread block.
// q/k/v stored f16.
// ---------------------------------------------------------------------------
__global__ __launch_bounds__(64, 2) void k_ln_qkv(
    const float* __restrict__ x,
    const unsigned short* __restrict__ wqkv_p, const float* __restrict__ bias3,
    unsigned short* __restrict__ q, unsigned short* __restrict__ k,
    unsigned short* __restrict__ v)
{
    const int t = threadIdx.x;
    const int lane = t & 63;
    const int nl = lane & 15, quad = lane >> 4;
    const int nbase = blockIdx.x * 16;
    const int node = nbase + nl;
    const bool nv = node < NN;

    float xv[64];
    float sum = 0.f, sq = 0.f;
    {
        const float* xp = x + (size_t)node * H + quad * 8;
        #pragma unroll
        for (int ks = 0; ks < 8; ++ks) {
            float4 x0 = {0.f,0.f,0.f,0.f}, x1 = {0.f,0.f,0.f,0.f};
            if (nv) {
                x0 = *(const float4*)(xp + ks * 32);
                x1 = *(const float4*)(xp + ks * 32 + 4);
            }
            xv[ks*8+0]=x0.x; xv[ks*8+1]=x0.y; xv[ks*8+2]=x0.z; xv[ks*8+3]=x0.w;
            xv[ks*8+4]=x1.x; xv[ks*8+5]=x1.y; xv[ks*8+6]=x1.z; xv[ks*8+7]=x1.w;
            sum += x0.x+x0.y+x0.z+x0.w + x1.x+x1.y+x1.z+x1.w;
            sq  += x0.x*x0.x+x0.y*x0.y+x0.z*x0.z+x0.w*x0.w
                 + x1.x*x1.x+x1.y*x1.y+x1.z*x1.z+x1.w*x1.w;
        }
    }
    sum += __shfl_xor(sum, 16); sum += __shfl_xor(sum, 32);
    sq  += __shfl_xor(sq, 16);  sq  += __shfl_xor(sq, 32);
    const float mu  = sum * (1.0f / H);
    const float var = sq * (1.0f / H) - mu * mu;
    const float rs  = rsqrtf(var + LN_EPS);

    short8 a_hi[8], a_lo[8];
    #pragma unroll
    for (int ks = 0; ks < 8; ++ks) {
        #pragma unroll
        for (int j = 0; j < 8; ++j) {
            const float z = (xv[ks*8+j] - mu) * rs;
            const unsigned short hh = f2bf(z);
            a_hi[ks][j] = (short)hh;
            a_lo[ks][j] = (short)f2bf(z - bf2f(hh));
        }
    }

    for (int mat = 0; mat < 3; ++mat) {
        unsigned short* outp = mat == 0 ? q : (mat == 1 ? k : v);
        const float* bp = bias3 + mat * 256;
        const unsigned short* wb = wqkv_p + (size_t)mat * 131072 + lane * 8;
        for (int tile = 0; tile < 16; ++tile) {
            const unsigned short* gb = wb + (size_t)tile * 8192;
            const float bbv = bp[tile * 16 + nl];
            f32x4 acc = {bbv, bbv, bbv, bbv};
            #pragma unroll
            for (int ks = 0; ks < 8; ++ks) {
                const short8 b_hi = *(const short8*)(gb + ks * 1024);
                const short8 b_lo = *(const short8*)(gb + ks * 1024 + 512);
                acc = __builtin_amdgcn_mfma_f32_16x16x32_bf16(a_hi[ks], b_hi, acc, 0, 0, 0);
                acc = __builtin_amdgcn_mfma_f32_16x16x32_bf16(a_lo[ks], b_hi, acc, 0, 0, 0);
                acc = __builtin_amdgcn_mfma_f32_16x16x32_bf16(a_hi[ks], b_lo, acc, 0, 0, 0);
            }
            #pragma unroll
            for (int r = 0; r < 4; ++r) {
                const int onode = nbase + quad * 4 + r;
                if (onode < NN)
                    outp[(size_t)onode * H + tile * 16 + nl] = f2h(acc[r]);
            }
        }
    }
}

// ---------------------------------------------------------------------------
// Counting sort of edges by dst: hist -> scan -> scatter
// ---------------------------------------------------------------------------
__global__ __launch_bounds__(256) void k_hist(const int* __restrict__ ei, int* __restrict__ hist) {
    int e = blockIdx.x * 256 + threadIdx.x;
    if (e < EE) atomicAdd(&hist[ei[EE + e]], 1);
}

__global__ __launch_bounds__(256) void k_scan1(const int* __restrict__ hist,
                                               int* __restrict__ cursor, int* __restrict__ bsum) {
    const int t = threadIdx.x, i = blockIdx.x * 256 + t;
    const int lane = t & 63, w = t >> 6;
    const int v = (i < NN) ? hist[i] : 0;
    int incl = v;
    #pragma unroll
    for (int off = 1; off < 64; off <<= 1) {
        int u = __shfl_up(incl, off);
        if (lane >= off) incl += u;
    }
    __shared__ int ws[4];
    if (lane == 63) ws[w] = incl;
    __syncthreads();
    int base = 0;
    #pragma unroll
    for (int j = 0; j < 4; ++j) if (j < w) base += ws[j];
    if (i < NN) cursor[i] = base + incl - v;
    if (t == 255) bsum[blockIdx.x] = base + incl;
}

__global__ __launch_bounds__(128) void k_scan2(int* __restrict__ bsum) {
    __shared__ int buf[128];
    const int t = threadIdx.x;
    const int v = (t < NB) ? bsum[t] : 0;
    buf[t] = v;
    __syncthreads();
    #pragma unroll
    for (int off = 1; off < 128; off <<= 1) {
        int add = (t >= off) ? buf[t - off] : 0;
        __syncthreads();
        buf[t] += add;
        __syncthreads();
    }
    if (t < NB) bsum[t] = buf[t] - v;
}

// scatter also materializes sorted src/dst/ew streams.
__global__ __launch_bounds__(256) void k_scatter(const int* __restrict__ ei,
                                                 const float* __restrict__ ew,
                                                 int* __restrict__ cursor,
                                                 const int* __restrict__ bsum,
                                                 int* __restrict__ perm,
                                                 int* __restrict__ srcs,
                                                 int* __restrict__ dsts,
                                                 float* __restrict__ ews) {
    int e = blockIdx.x * 256 + threadIdx.x;
    if (e < EE) {
        int s = ei[e];
        int d = ei[EE + e];
        int pos = atomicAdd(&cursor[d], 1) + bsum[d >> 8];
        perm[pos] = e;
        srcs[pos] = s;
        dsts[pos] = d;
        ews[pos] = ew[e];
    }
}

// ---------------------------------------------------------------------------
// K2: round-14 -- BARRIER-FREE. After rounds 6/8 the four waves share only
// the staged weight image; weights are L2-resident (128KB total across 5000
// blocks), so B-fragments are read DIRECT from global (fragment-linear pack,
// 16B/lane coalesced) and w_region + all 8 __syncthreads are deleted. Each
// wave owns 16 edges end-to-end (its ea rows = its MFMA A rows = its dks
// rows = its attn rows): waves drift freely through phases, covering each
// other's gather latency. LDS 65.3 -> 33.5 KB => 4 blocks/CU (16 waves/CU).
// ---------------------------------------------------------------------------
__global__ __launch_bounds__(256, 4) void k_edge(
    const unsigned short* __restrict__ q16, const unsigned short* __restrict__ k16,
    const unsigned short* __restrict__ v16,
    const float* __restrict__ ea,
    const unsigned short* __restrict__ wdk_p, const float* __restrict__ bdk,
    const unsigned short* __restrict__ wdv_p, const float* __restrict__ bdv,
    const int* __restrict__ perm, const int* __restrict__ srcs,
    const int* __restrict__ dsts, const float* __restrict__ ews,
    float* __restrict__ agg)
{
    __shared__ __align__(16) unsigned short dks_all[4 * 16 * 256];  // 32 KB
    __shared__ int   srcw_all[4 * 16], dstw_all[4 * 16];
    __shared__ float attw_all[4 * 16];

    const int t    = threadIdx.x;
    const int bi   = blockIdx.x;
    const int wave = t >> 6, lane = t & 63;
    // XCD-contiguous chunks; this wave's private 16-edge strip
    const int eb2  = (((bi & 7) * 625 + (bi >> 3)) * 4 + wave) * 16;

    unsigned short* dksw = dks_all + wave * 4096;
    int*   srcw = srcw_all + wave * 16;
    int*   dstw = dstw_all + wave * 16;
    float* attw = attw_all + wave * 16;

    const int nl = lane & 15, quad = lane >> 4;
    const int tx = lane & 31, ty2 = lane >> 5;
    const int h0 = tx * 4, e0l = ty2 * 8;

    if (lane < 16) {
        srcw[lane] = srcs[eb2 + lane];
        dstw[lane] = dsts[eb2 + lane];
    }

    // ea A-fragments from global, in-register hi/lo split (row nl = own edge)
    short8 a_hi[2], a_lo[2];
    {
        const int e = perm[eb2 + nl];
        const float* ap = ea + (size_t)e * R + quad * 8;
        #pragma unroll
        for (int ks = 0; ks < 2; ++ks) {
            const f32x4 x0 = *(const f32x4*)(ap + ks * 32);
            const f32x4 x1 = *(const f32x4*)(ap + ks * 32 + 4);
            const float zz[8] = {x0[0], x0[1], x0[2], x0[3], x1[0], x1[1], x1[2], x1[3]};
            #pragma unroll
            for (int j = 0; j < 8; ++j) {
                const unsigned short hv = f2bf(zz[j]);
                a_hi[ks][j] = (short)hv;
                a_lo[ks][j] = (short)f2bf(zz[j] - bf2f(hv));
            }
        }
    }

    // MFMA with B-fragments direct from global (L2-hot), output -> own dks rows
    #define MFMA_DKS(IMG, BIAS, HALF)                                                 \
    {                                                                                 \
        const unsigned short* img_ = (IMG);                                           \
        f32x4 accA[8];                                                                \
        _Pragma("unroll")                                                             \
        for (int tt = 0; tt < 8; ++tt) {                                              \
            short8 b_hi[2], b_lo[2];                                                  \
            _Pragma("unroll")                                                         \
            for (int ks = 0; ks < 2; ++ks) {                                          \
                const unsigned short* fb = img_ + (tt * 2 + ks) * 1024 + lane * 8;    \
                b_hi[ks] = *(const short8*)fb;                                        \
                b_lo[ks] = *(const short8*)(fb + 512);                                \
            }                                                                         \
            const float bb = (BIAS)[(HALF) * 128 + tt * 16 + nl];                     \
            f32x4 acc = {bb, bb, bb, bb};                                             \
            _Pragma("unroll")                                                         \
            for (int ks = 0; ks < 2; ++ks) {                                          \
                acc = __builtin_amdgcn_mfma_f32_16x16x32_bf16(a_hi[ks], b_hi[ks], acc, 0, 0, 0); \
                acc = __builtin_amdgcn_mfma_f32_16x16x32_bf16(a_lo[ks], b_hi[ks], acc, 0, 0, 0); \
                acc = __builtin_amdgcn_mfma_f32_16x16x32_bf16(a_hi[ks], b_lo[ks], acc, 0, 0, 0); \
            }                                                                         \
            accA[tt] = acc;                                                           \
        }                                                                             \
        _Pragma("unroll")                                                             \
        for (int tt = 0; tt < 8; ++tt)                                                \
            _Pragma("unroll")                                                         \
            for (int r = 0; r < 4; ++r)                                               \
                dksw[dh_idx(quad * 4 + r, (HALF) * 128 + tt * 16 + nl)] =             \
                    f2h(silu_f(accA[tt][r]));                                         \
    }

    MFMA_DKS(wdk_p,         bdk, 0);
    MFMA_DKS(wdk_p + 16384, bdk, 1);

    // ---- pass A: f16 q/k gathers, full 256-wide rows, one reduce/edge ----
    {
        float qv[8];
        int pd = -1;
        #pragma unroll
        for (int i = 0; i < 8; ++i) {
            const int d = dstw[e0l + i], s = srcw[e0l + i];
            if (d != pd) {
                const ushort4 q0 = *(const ushort4*)(q16 + (size_t)d * H + h0);
                const ushort4 q1 = *(const ushort4*)(q16 + (size_t)d * H + 128 + h0);
                qv[0] = h2f(q0.x); qv[1] = h2f(q0.y); qv[2] = h2f(q0.z); qv[3] = h2f(q0.w);
                qv[4] = h2f(q1.x); qv[5] = h2f(q1.y); qv[6] = h2f(q1.z); qv[7] = h2f(q1.w);
                pd = d;
            }
            const ushort4 k0 = *(const ushort4*)(k16 + (size_t)s * H + h0);
            const ushort4 k1 = *(const ushort4*)(k16 + (size_t)s * H + 128 + h0);
            const ushort4 d40 = *(const ushort4*)&dksw[dh_idx(e0l + i, h0)];
            const ushort4 d41 = *(const ushort4*)&dksw[dh_idx(e0l + i, 128 + h0)];
            float part = qv[0] * h2f(k0.x) * h2f(d40.x) + qv[1] * h2f(k0.y) * h2f(d40.y)
                       + qv[2] * h2f(k0.z) * h2f(d40.z) + qv[3] * h2f(k0.w) * h2f(d40.w)
                       + qv[4] * h2f(k1.x) * h2f(d41.x) + qv[5] * h2f(k1.y) * h2f(d41.y)
                       + qv[6] * h2f(k1.z) * h2f(d41.z) + qv[7] * h2f(k1.w) * h2f(d41.w);
            #pragma unroll
            for (int off = 16; off; off >>= 1) part += __shfl_xor(part, off);
            if (tx == 0) attw[e0l + i] = part;
        }
    }

    // attn finalize: own wave's 16 rows (in-wave LDS ordering, no barrier)
    if (lane < 16) {
        const float rr = ews[eb2 + lane];
        const float cut = (rr < 5.0f) ? 0.5f * (__cosf(rr * 0.6283185307f) + 1.0f) : 0.0f;
        attw[lane] = silu_f(attw[lane]) * cut;
    }

    MFMA_DKS(wdv_p,         bdv, 0);
    MFMA_DKS(wdv_p + 16384, bdv, 1);

    // ---- pass B: f16 v gathers, run-flush row-walk over 256 cols ----
    {
        float4 m0 = {0.f,0.f,0.f,0.f}, m1 = {0.f,0.f,0.f,0.f};
        int cur_d = -1;
        #pragma unroll
        for (int i = 0; i < 8; ++i) {
            const int d = dstw[e0l + i], s = srcw[e0l + i];
            const float a = attw[e0l + i];
            const ushort4 v0 = *(const ushort4*)(v16 + (size_t)s * H + h0);
            const ushort4 v1 = *(const ushort4*)(v16 + (size_t)s * H + 128 + h0);
            const ushort4 d40 = *(const ushort4*)&dksw[dh_idx(e0l + i, h0)];
            const ushort4 d41 = *(const ushort4*)&dksw[dh_idx(e0l + i, 128 + h0)];
            const float w0x = h2f(v0.x) * h2f(d40.x) * a, w0y = h2f(v0.y) * h2f(d40.y) * a;
            const float w0z = h2f(v0.z) * h2f(d40.z) * a, w0w = h2f(v0.w) * h2f(d40.w) * a;
            const float w1x = h2f(v1.x) * h2f(d41.x) * a, w1y = h2f(v1.y) * h2f(d41.y) * a;
            const float w1z = h2f(v1.z) * h2f(d41.z) * a, w1w = h2f(v1.w) * h2f(d41.w) * a;
            if (d != cur_d) {
                if (cur_d >= 0) {
                    float* dp = agg + (size_t)cur_d * H;
                    atomicAdd(dp + h0 + 0, m0.x); atomicAdd(dp + h0 + 1, m0.y);
                    atomicAdd(dp + h0 + 2, m0.z); atomicAdd(dp + h0 + 3, m0.w);
                    atomicAdd(dp + 128 + h0 + 0, m1.x); atomicAdd(dp + 128 + h0 + 1, m1.y);
                    atomicAdd(dp + 128 + h0 + 2, m1.z); atomicAdd(dp + 128 + h0 + 3, m1.w);
                }
                m0.x = w0x; m0.y = w0y; m0.z = w0z; m0.w = w0w;
                m1.x = w1x; m1.y = w1y; m1.z = w1z; m1.w = w1w;
                cur_d = d;
            } else {
                m0.x += w0x; m0.y += w0y; m0.z += w0z; m0.w += w0w;
                m1.x += w1x; m1.y += w1y; m1.z += w1z; m1.w += w1w;
            }
        }
        {
            float* dp = agg + (size_t)cur_d * H;
            atomicAdd(dp + h0 + 0, m0.x); atomicAdd(dp + h0 + 1, m0.y);
            atomicAdd(dp + h0 + 2, m0.z); atomicAdd(dp + h0 + 3, m0.w);
            atomicAdd(dp + 128 + h0 + 0, m1.x); atomicAdd(dp + 128 + h0 + 1, m1.y);
            atomicAdd(dp + 128 + h0 + 2, m1.z); atomicAdd(dp + 128 + h0 + 3, m1.w);
        }
    }
    #undef MFMA_DKS
}

// ---------------------------------------------------------------------------
// K3: out = x + agg @ Wo'^T + bo via split-bf16 MFMA. 16 nodes / 64-thr block.
// ---------------------------------------------------------------------------
__global__ __launch_bounds__(64, 2) void k_out(
    const float* __restrict__ aggm, const unsigned short* __restrict__ wo_p,
    const float* __restrict__ bo, const float* __restrict__ x, float* __restrict__ out)
{
    const int t = threadIdx.x;
    const int lane = t & 63;
    const int nl = lane & 15, quad = lane >> 4;
    const int nbase = blockIdx.x * 16;
    const int node = nbase + nl;
    const bool nv = node < NN;

    short8 a_hi[8], a_lo[8];
    {
        const float* ap = aggm + (size_t)node * H + quad * 8;
        #pragma unroll
        for (int ks = 0; ks < 8; ++ks) {
            float4 x0 = {0.f,0.f,0.f,0.f}, x1 = {0.f,0.f,0.f,0.f};
            if (nv) { x0 = *(const float4*)(ap + ks * 32); x1 = *(const float4*)(ap + ks * 32 + 4); }
            const float zz[8] = {x0.x,x0.y,x0.z,x0.w,x1.x,x1.y,x1.z,x1.w};
            #pragma unroll
            for (int j = 0; j < 8; ++j) {
                const unsigned short hh = f2bf(zz[j]);
                a_hi[ks][j] = (short)hh;
                a_lo[ks][j] = (short)f2bf(zz[j] - bf2f(hh));
            }
        }
    }
    for (int tile = 0; tile < 16; ++tile) {
        const unsigned short* gb = wo_p + (size_t)tile * 8192 + lane * 8;
        const float bbv = bo[tile * 16 + nl];
        f32x4 acc = {bbv, bbv, bbv, bbv};
        #pragma unroll
        for (int ks = 0; ks < 8; ++ks) {
            const short8 b_hi = *(const short8*)(gb + ks * 1024);
            const short8 b_lo = *(const short8*)(gb + ks * 1024 + 512);
            acc = __builtin_amdgcn_mfma_f32_16x16x32_bf16(a_hi[ks], b_hi, acc, 0, 0, 0);
            acc = __builtin_amdgcn_mfma_f32_16x16x32_bf16(a_lo[ks], b_hi, acc, 0, 0, 0);
            acc = __builtin_amdgcn_mfma_f32_16x16x32_bf16(a_hi[ks], b_lo, acc, 0, 0, 0);
        }
        #pragma unroll
        for (int r = 0; r < 4; ++r) {
            const int onode = nbase + quad * 4 + r;
            if (onode < NN) {
                const size_t oi = (size_t)onode * H + tile * 16 + nl;
                out[oi] = x[oi] + acc[r];
            }
        }
    }
}

extern "C" void kernel_launch(void* const* d_in, const int* in_sizes, int n_in,
                              void* d_out, int out_size, void* d_ws, size_t ws_size,
                              hipStream_t stream) {
    const float* x   = (const float*)d_in[0];
    const int*   ei  = (const int*)d_in[1];
    const float* ew  = (const float*)d_in[2];
    const float* ea  = (const float*)d_in[3];
    const float* g   = (const float*)d_in[4];
    const float* b   = (const float*)d_in[5];
    const float* Wq  = (const float*)d_in[6];  const float* bq  = (const float*)d_in[7];
    const float* Wk  = (const float*)d_in[8];  const float* bk  = (const float*)d_in[9];
    const float* Wv  = (const float*)d_in[10]; const float* bv  = (const float*)d_in[11];
    const float* Wo  = (const float*)d_in[12]; const float* bo  = (const float*)d_in[13];
    const float* Wdk = (const float*)d_in[14]; const float* bdk = (const float*)d_in[15];
    const float* Wdv = (const float*)d_in[16]; const float* bdv = (const float*)d_in[17];

    unsigned short* q16 = (unsigned short*)d_ws;
    unsigned short* k16 = q16 + (size_t)NN * H;
    unsigned short* v16 = k16 + (size_t)NN * H;
    float* agg  = (float*)(v16 + (size_t)NN * H);
    int*   hist = (int*)(agg + (size_t)NN * H);
    int*   cur  = hist + NN;
    int*   bsum = cur + NN;
    int*   perm = bsum + 128;
    int*   srcs = perm + EE;
    int*   dsts = srcs + EE;
    float* ews  = (float*)(dsts + EE);
    unsigned short* wqkv_p = (unsigned short*)(ews + EE);
    unsigned short* wo_p   = wqkv_p + 393216;
    unsigned short* wdk_p  = wo_p + 131072;
    unsigned short* wdv_p  = wdk_p + 32768;
    float* bias3 = (float*)(wdv_p + 32768);

    hipMemsetAsync(agg, 0, (size_t)NN * H * sizeof(float), stream);
    k_prep<<<226, 256, 0, stream>>>(Wq, Wk, Wv, Wo, g, b, bq, bk, bv, Wdk, Wdv,
                                    wqkv_p, wo_p, wdk_p, wdv_p, bias3, hist);
    k_hist<<<EE / 256, 256, 0, stream>>>(ei, hist);
    k_ln_qkv<<<(NN + 15) / 16, 64, 0, stream>>>(x, wqkv_p, bias3, q16, k16, v16);
    k_scan1<<<NB, 256, 0, stream>>>(hist, cur, bsum);
    k_scan2<<<1, 128, 0, stream>>>(bsum);
    k_scatter<<<EE / 256, 256, 0, stream>>>(ei, ew, cur, bsum, perm, srcs, dsts, ews);
    k_edge<<<EE / 64, 256, 0, stream>>>(q16, k16, v16, ea, wdk_p, bdk, wdv_p, bdv,
                                        perm, srcs, dsts, ews, agg);
    k_out<<<(NN + 15) / 16, 64, 0, stream>>>(agg, wo_p, bo, x, (float*)d_out);
}